// Round 4
// baseline (104.602 us; speedup 1.0000x reference)
//
#include <hip/hip_runtime.h>
#include <math.h>

#define NPTS   8192
#define DDIM   128
#define NBLK   64            // 8192 / 128 row-blocks
#define NTRI   2080          // NBLK*(NBLK+1)/2 working blocks
#define TPB    4             // tiles per block (2080 = 520 * 4 exactly)
#define GRID   (NTRI / TPB)  // 520

using short8 = __attribute__((ext_vector_type(8))) short;
using f32x4  = __attribute__((ext_vector_type(4))) float;

__device__ __forceinline__ unsigned short f2bf(float f) {
    unsigned int u = __float_as_uint(f);
    u += 0x7fffu + ((u >> 16) & 1u);
    return (unsigned short)(u >> 16);
}
__device__ __forceinline__ float bf2f(unsigned short s) {
    return __uint_as_float(((unsigned int)s) << 16);
}

// async 16B/lane global->LDS DMA (dest = wave-uniform base + lane*16)
__device__ __forceinline__ void gld_lds16(const unsigned short* g, unsigned short* l) {
    __builtin_amdgcn_global_load_lds(
        (const __attribute__((address_space(1))) unsigned int*)g,
        (__attribute__((address_space(3))) unsigned int*)l,
        16, 0, 0);
}

// --- kernel 1: convert X -> bf16 once; sq[i] = ||bf16(x_i)||^2 ---
__global__ __launch_bounds__(256) void prep_kernel(
    const float* __restrict__ X, unsigned short* __restrict__ Xbf,
    float* __restrict__ sq)
{
    const int wave = threadIdx.x >> 6, lane = threadIdx.x & 63;
    const int row  = blockIdx.x * 4 + wave;
    float2 v = *(const float2*)(X + (size_t)row * DDIM + lane * 2);
    unsigned short a = f2bf(v.x), b = f2bf(v.y);
    float fa = bf2f(a), fb = bf2f(b);
    float s = fa * fa + fb * fb;
    *(ushort2*)(Xbf + (size_t)row * DDIM + lane * 2) = make_ushort2(a, b);
#pragma unroll
    for (int off = 32; off > 0; off >>= 1) s += __shfl_down(s, off);
    if (lane == 0) sq[row] = s;
}

// --- kernel 2: persistent 4-tile blocks, SINGLE-buffered 64 KB LDS (2 blocks/CU),
// T14 register prefetch: next tile's B panel is loaded global->REGS during compute
// (no LDS writes in flight during ds_reads -> no bank-conflict overlap), then
// written to LDS in a short write-phase between two barriers. A panel is reused
// across the block's 4 consecutive tiles; on a bi change it's restaged via DMA
// in the write phase (<=1x per block).
// Panel layout (ushort idx): A=[0,16384), B=[16384,32768).
// Within a panel: tile[r][s] = X[row0+r][8*(s ^ (r&7))]  (XOR swizzle, s=16B slot)
__global__ __launch_bounds__(256) void pair_kernel(
    const unsigned short* __restrict__ Xbf, const int* __restrict__ lab,
    const float* __restrict__ sq, float* __restrict__ slots /* [2][NTRI] */)
{
    const int k0 = blockIdx.x * TPB;
    int bi = (int)((129.0f - sqrtf((float)(16641 - 8 * k0))) * 0.5f);
    if (bi < 0) bi = 0;
    while (64 * (bi + 1) - ((bi + 1) * bi) / 2 <= k0) ++bi;   // O(bi+1) <= k0
    while (64 * bi - (bi * (bi - 1)) / 2 > k0) --bi;          // O(bi)   >  k0
    int bj = bi + (k0 - (64 * bi - (bi * (bi - 1)) / 2));

    __shared__ unsigned short tile[32768];   // 64 KB: A = [0,16384), B = [16384,32768)
    __shared__ float sSqA[128], sSqB[128];
    __shared__ int   sLabA[128], sLabB[128];
    __shared__ float rP[4], rN[4];

    const int tid  = threadIdx.x;
    const int rloc = tid >> 4;                        // 0..15: row within 16-row stripe
    const int cswz = ((tid & 15) ^ (rloc & 7)) * 8;   // pre-swizzled source column
    const int lws  = (tid & ~63) * 8;                 // wave-uniform LDS ushort offset

    // DMA-stage one 128x128 bf16 panel (8 DMAs/wave, 16B/lane, linear LDS dest)
    auto stage = [&](int row0, int panelBase) {
        const unsigned short* g = Xbf + (size_t)(row0 + rloc) * DDIM + cswz;
        unsigned short* l = &tile[panelBase + lws];
#pragma unroll
        for (int i = 0; i < 8; ++i)
            gld_lds16(g + (size_t)i * 16 * DDIM, l + i * 2048);
    };

    // prologue: DMA tile 0 (A, B) + publish sq/lab; full drain once per block
    stage(bi * 128, 0);
    stage(bj * 128, 16384);
    {
        int r = (tid < 128) ? (bi * 128 + tid) : (bj * 128 + (tid - 128));
        float sv = sq[r]; int lv = lab[r];
        if (tid < 128) { sSqA[tid] = sv;        sLabA[tid] = lv; }
        else           { sSqB[tid - 128] = sv;  sLabB[tid - 128] = lv; }
    }
    __syncthreads();

    const int wave = tid >> 6, lane = tid & 63;
    const int quad = lane >> 4, rr = lane & 15;
    const int wr = wave >> 1, wc = wave & 1;
    const int r7 = rr & 15 & 7;

    const unsigned short* tA = &tile[(size_t)(wr * 64 + rr) * 128];
    const unsigned short* tB = &tile[16384 + (size_t)(wc * 64 + rr) * 128];

    // B reg-stage -> LDS write mapping: chunk c covers rows c*16 + (tid>>4),
    // slot (tid&15); swizzled slot is invariant across chunks. Conflict-free
    // (8 accesses/bank per ds_write_b128 instruction = minimum).
    const int wrow = tid >> 4;
    const int wswz = (tid & 15) ^ (wrow & 7);

    int bi_c = bi, bj_c = bj;

#pragma unroll
    for (int t = 0; t < TPB; ++t) {
        const bool last = (t == TPB - 1);
        int bi_n = bi_c, bj_n = bj_c + 1;
        if (bj_n == NBLK) { bi_n = bi_c + 1; bj_n = bi_n; }
        const bool aChg = (bi_n != bi_c);

        // ---- issue next tile's B panel to REGISTERS (overlaps all of compute) ----
        short8 rB[8];
        float sqN = 0.f; int labN = 0;
        if (!last) {
            const unsigned short* gB = Xbf + (size_t)bj_n * 128 * DDIM + tid * 8;
#pragma unroll
            for (int c = 0; c < 8; ++c)
                rB[c] = *(const short8*)(gB + c * 2048);
            if (tid >= 128)   { sqN = sq[bj_n * 128 + tid - 128]; labN = lab[bj_n * 128 + tid - 128]; }
            else if (aChg)    { sqN = sq[bi_n * 128 + tid];       labN = lab[bi_n * 128 + tid]; }
            __builtin_amdgcn_sched_barrier(0);   // pin load issue before compute
        }

        // ---- compute tile t from single-buffered LDS ----
        f32x4 acc[4][4];
#pragma unroll
        for (int i = 0; i < 4; ++i)
#pragma unroll
            for (int j = 0; j < 4; ++j)
                acc[i][j] = (f32x4){0.f, 0.f, 0.f, 0.f};

#pragma unroll
        for (int kc = 0; kc < 4; ++kc) {    // K = 128 in 4 chunks of 32
            const int s = (((kc * 4 + quad) ^ r7)) * 8;   // swizzled 16B slot
            short8 a[4], b[4];
#pragma unroll
            for (int u = 0; u < 4; ++u)
                a[u] = *(const short8*)(tA + u * 16 * 128 + s);
#pragma unroll
            for (int u = 0; u < 4; ++u)
                b[u] = *(const short8*)(tB + u * 16 * 128 + s);
#pragma unroll
            for (int i = 0; i < 4; ++i)
#pragma unroll
                for (int j = 0; j < 4; ++j)
                    acc[i][j] = __builtin_amdgcn_mfma_f32_16x16x32_bf16(a[i], b[j], acc[i][j], 0, 0, 0);
        }

        // epilogue. C/D layout: col = lane&15, row = quad*4 + reg (verified)
        float sb[4]; int lbv[4];
#pragma unroll
        for (int j = 0; j < 4; ++j) {
            int cl = wc * 64 + j * 16 + rr;
            sb[j]  = sSqB[cl];
            lbv[j] = sLabB[cl];
        }

        float posS = 0.f, dmin = 1e30f;
#pragma unroll
        for (int i = 0; i < 4; ++i) {
#pragma unroll
            for (int rg = 0; rg < 4; ++rg) {
                int   rl = wr * 64 + i * 16 + quad * 4 + rg;
                float sa = sSqA[rl];
                int   la = sLabA[rl];
#pragma unroll
                for (int j = 0; j < 4; ++j) {
                    float d = fmaxf(sa + sb[j] - 2.0f * acc[i][j][rg], 0.0f);
                    bool same = (la == lbv[j]);
                    posS += same ? d : 0.f;
                    dmin = fminf(dmin, same ? 1e30f : d);
                }
            }
        }

        float negS = 0.f;
        if (__any(dmin + 1e-9f < 4.0f)) {   // rare: some hinge term is nonzero
#pragma unroll
            for (int i = 0; i < 4; ++i) {
#pragma unroll
                for (int rg = 0; rg < 4; ++rg) {
                    int   rl = wr * 64 + i * 16 + quad * 4 + rg;
                    float sa = sSqA[rl];
                    int   la = sLabA[rl];
#pragma unroll
                    for (int j = 0; j < 4; ++j) {
                        float d = fmaxf(sa + sb[j] - 2.0f * acc[i][j][rg], 0.0f);
                        float h = fmaxf(2.0f - sqrtf(d + 1e-9f), 0.f);
                        negS += (la == lbv[j]) ? 0.f : h * h;
                    }
                }
            }
        }

        const float factor = (bi_c == bj_c) ? 1.0f : 2.0f;
        posS *= factor; negS *= factor;

#pragma unroll
        for (int off = 32; off > 0; off >>= 1) {
            posS += __shfl_down(posS, off);
            negS += __shfl_down(negS, off);
        }
        if (lane == 0) { rP[wave] = posS; rN[wave] = negS; }

        // ---- read-barrier: all LDS reads of tile t complete past this point ----
        asm volatile("s_waitcnt lgkmcnt(0)" ::: "memory");
        __builtin_amdgcn_s_barrier();
        __builtin_amdgcn_sched_barrier(0);

        if (tid == 0) {
            slots[k0 + t]        = rP[0] + rP[1] + rP[2] + rP[3];
            slots[NTRI + k0 + t] = rN[0] + rN[1] + rN[2] + rN[3];
        }

        // ---- write-phase: commit next tile's panels, then release ----
        if (!last) {
            asm volatile("s_waitcnt vmcnt(0)" ::: "memory");   // rB/sqN arrived during compute
#pragma unroll
            for (int c = 0; c < 8; ++c)
                *(short8*)(&tile[16384 + (size_t)(c * 16 + wrow) * 128 + wswz * 8]) = rB[c];
            if (tid >= 128)   { sSqB[tid - 128] = sqN; sLabB[tid - 128] = labN; }
            else if (aChg)    { sSqA[tid] = sqN;       sLabA[tid] = labN; }
            if (aChg) {
                stage(bi_n * 128, 0);                  // rare A restage via DMA
                asm volatile("s_waitcnt vmcnt(0) lgkmcnt(0)" ::: "memory");
            } else {
                asm volatile("s_waitcnt lgkmcnt(0)" ::: "memory");
            }
            __builtin_amdgcn_s_barrier();
            __builtin_amdgcn_sched_barrier(0);
        }

        bi_c = bi_n; bj_c = bj_n;
    }
}

// --- kernel 3: label histogram (exact num_pos) + slot reduce + combine ---
__global__ __launch_bounds__(1024) void finalize_kernel(
    const float* __restrict__ slots, const int* __restrict__ lab,
    float* __restrict__ out)
{
    __shared__ int   hist[64];
    __shared__ float sP[16], sN[16];
    const int tid = threadIdx.x;
    if (tid < 64) hist[tid] = 0;
    __syncthreads();
    for (int i = tid; i < NPTS; i += 1024) atomicAdd(&hist[lab[i]], 1);

    float p = 0.f, n = 0.f;
    for (int i = tid; i < NTRI; i += 1024) { p += slots[i]; n += slots[NTRI + i]; }
#pragma unroll
    for (int off = 32; off > 0; off >>= 1) {
        p += __shfl_down(p, off);
        n += __shfl_down(n, off);
    }
    const int wave = tid >> 6, lane = tid & 63;
    if (lane == 0) { sP[wave] = p; sN[wave] = n; }
    __syncthreads();
    if (tid == 0) {
        long long np = 0;
        for (int c = 0; c < 64; ++c) np += (long long)hist[c] * hist[c];
        float tp = 0.f, tn = 0.f;
#pragma unroll
        for (int w = 0; w < 16; ++w) { tp += sP[w]; tn += sN[w]; }
        double dnp = (double)np;
        double dnn = (double)NPTS * (double)NPTS - dnp;
        double pt = (dnp > 0.0) ? 0.5 * (double)tp / dnp : 0.0;
        double nt = (dnn > 0.0) ? 0.5 * (double)tn / dnn : 0.0;
        out[0] = (float)(pt + nt);
    }
}

extern "C" void kernel_launch(void* const* d_in, const int* in_sizes, int n_in,
                              void* d_out, int out_size, void* d_ws, size_t ws_size,
                              hipStream_t stream) {
    const float* X   = (const float*)d_in[0];
    const int*   lab = (const int*)d_in[1];
    float*       out = (float*)d_out;

    char* ws = (char*)d_ws;
    unsigned short* Xbf   = (unsigned short*)(ws);                      // 2 MB
    float*          sq    = (float*)(ws + 2 * 1024 * 1024);             // 32 KB
    float*          slots = (float*)(ws + 2 * 1024 * 1024 + 32 * 1024); // 16.6 KB

    prep_kernel<<<NPTS / 4, 256, 0, stream>>>(X, Xbf, sq);
    pair_kernel<<<GRID, 256, 0, stream>>>(Xbf, lab, sq, slots);
    finalize_kernel<<<1, 1024, 0, stream>>>(slots, lab, out);
}

// Round 5
// 87.785 us; speedup vs baseline: 1.1916x; 1.1916x over previous
//
#include <hip/hip_runtime.h>
#include <math.h>

#define NPTS   8192
#define DDIM   128
#define NBLK2  32            // 8192 / 256 row-super-blocks
#define NTRI2  528           // NBLK2*(NBLK2+1)/2 super-tiles

using short8 = __attribute__((ext_vector_type(8))) short;
using f32x4  = __attribute__((ext_vector_type(4))) float;

__device__ __forceinline__ unsigned short f2bf(float f) {
    unsigned int u = __float_as_uint(f);
    u += 0x7fffu + ((u >> 16) & 1u);
    return (unsigned short)(u >> 16);
}
__device__ __forceinline__ float bf2f(unsigned short s) {
    return __uint_as_float(((unsigned int)s) << 16);
}

// async 16B/lane global->LDS DMA (dest = wave-uniform base + lane*16)
__device__ __forceinline__ void gld_lds16(const unsigned short* g, unsigned short* l) {
    __builtin_amdgcn_global_load_lds(
        (const __attribute__((address_space(1))) unsigned int*)g,
        (__attribute__((address_space(3))) unsigned int*)l,
        16, 0, 0);
}

// --- kernel 1: convert X -> bf16 once; sq[i] = ||bf16(x_i)||^2 ---
__global__ __launch_bounds__(256) void prep_kernel(
    const float* __restrict__ X, unsigned short* __restrict__ Xbf,
    float* __restrict__ sq)
{
    const int wave = threadIdx.x >> 6, lane = threadIdx.x & 63;
    const int row  = blockIdx.x * 4 + wave;
    float2 v = *(const float2*)(X + (size_t)row * DDIM + lane * 2);
    unsigned short a = f2bf(v.x), b = f2bf(v.y);
    float fa = bf2f(a), fb = bf2f(b);
    float s = fa * fa + fb * fb;
    *(ushort2*)(Xbf + (size_t)row * DDIM + lane * 2) = make_ushort2(a, b);
#pragma unroll
    for (int off = 32; off > 0; off >>= 1) s += __shfl_down(s, off);
    if (lane == 0) sq[row] = s;
}

// --- kernel 2: 256x256 super-tiles, 512 threads (8 waves, 2x4), single stage +
// single drain per block. 4x the MFMA work per prologue/epilogue round-trip vs
// the 128^2 version; staging bytes halved (128 KB per 4 tile-equivalents).
// LDS panels (ushort idx): A=[0,32768), B=[32768,65536).
// Panel layout: tile[r][s] = X[row0+r][8*(s ^ (r&7))]  (XOR swizzle, s=16B slot)
__global__ __launch_bounds__(512, 2) void pair_kernel(
    const unsigned short* __restrict__ Xbf, const int* __restrict__ lab,
    const float* __restrict__ sq, float* __restrict__ slots /* [2][NTRI2] */)
{
    const int k = blockIdx.x;
    // O(b) = 32b - b(b-1)/2 ; bi = floor((65 - sqrt(65^2 - 8k))/2), then fix up
    int bi = (int)((65.0f - sqrtf((float)(4225 - 8 * k))) * 0.5f);
    if (bi < 0) bi = 0;
    while (32 * (bi + 1) - ((bi + 1) * bi) / 2 <= k) ++bi;   // O(bi+1) <= k
    while (32 * bi - (bi * (bi - 1)) / 2 > k) --bi;          // O(bi)   >  k
    const int bj = bi + (k - (32 * bi - (bi * (bi - 1)) / 2));

    __shared__ unsigned short tile[65536];   // 128 KB: A=[0,32768), B=[32768,65536)
    __shared__ float sSqA[256], sSqB[256];
    __shared__ int   sLabA[256], sLabB[256];
    __shared__ float rP[8], rN[8];

    const int tid   = threadIdx.x;
    const int rowA0 = bi * 256;
    const int rowB0 = bj * 256;

    // ---- async staging of both 256x128 bf16 panels (16 DMAs/thread-slot) ----
    {
        const int rloc = tid >> 4;                        // 0..31: row within 32-row stripe
        const int cswz = ((tid & 15) ^ (rloc & 7)) * 8;   // pre-swizzled source column
        const unsigned short* gA = Xbf + (size_t)(rowA0 + rloc) * DDIM + cswz;
        const unsigned short* gB = Xbf + (size_t)(rowB0 + rloc) * DDIM + cswz;
        unsigned short* lA = &tile[(tid & ~63) * 8];          // wave-uniform base
        unsigned short* lB = &tile[32768 + (tid & ~63) * 8];
#pragma unroll
        for (int i = 0; i < 8; ++i)                       // rows i*32 + rloc
            gld_lds16(gA + (size_t)i * 32 * DDIM, lA + i * 4096);
#pragma unroll
        for (int i = 0; i < 8; ++i)
            gld_lds16(gB + (size_t)i * 32 * DDIM, lB + i * 4096);
    }

    // sq/lab publish (512 threads cover 256 A + 256 B exactly)
    if (tid < 256) { sSqA[tid] = sq[rowA0 + tid];        sLabA[tid] = lab[rowA0 + tid]; }
    else           { sSqB[tid - 256] = sq[rowB0 + tid - 256];
                     sLabB[tid - 256] = lab[rowB0 + tid - 256]; }
    __syncthreads();   // drains DMA (vmcnt) + LDS writes; the only staging barrier

    const int wave = tid >> 6, lane = tid & 63;
    const int quad = lane >> 4, rr = lane & 15;
    const int wr = wave >> 2, wc = wave & 3;    // 2 x 4 wave grid, 128x64 per wave
    const int r7 = rr & 7;

    const unsigned short* tA = &tile[(size_t)(wr * 128 + rr) * 128];
    const unsigned short* tB = &tile[32768 + (size_t)(wc * 64 + rr) * 128];

    f32x4 acc[8][4];
#pragma unroll
    for (int i = 0; i < 8; ++i)
#pragma unroll
        for (int j = 0; j < 4; ++j)
            acc[i][j] = (f32x4){0.f, 0.f, 0.f, 0.f};

#pragma unroll
    for (int kc = 0; kc < 4; ++kc) {            // K = 128 in 4 chunks of 32
        const int s = (((kc * 4 + quad) ^ r7)) * 8;   // swizzled 16B slot
        short8 b4[4];
#pragma unroll
        for (int u = 0; u < 4; ++u)
            b4[u] = *(const short8*)(tB + u * 16 * 128 + s);
        short8 a0[4];
#pragma unroll
        for (int u = 0; u < 4; ++u)
            a0[u] = *(const short8*)(tA + u * 16 * 128 + s);
#pragma unroll
        for (int i = 0; i < 4; ++i)
#pragma unroll
            for (int j = 0; j < 4; ++j)
                acc[i][j] = __builtin_amdgcn_mfma_f32_16x16x32_bf16(a0[i], b4[j], acc[i][j], 0, 0, 0);
        short8 a1[4];
#pragma unroll
        for (int u = 0; u < 4; ++u)
            a1[u] = *(const short8*)(tA + (4 + u) * 16 * 128 + s);
#pragma unroll
        for (int i = 0; i < 4; ++i)
#pragma unroll
            for (int j = 0; j < 4; ++j)
                acc[4 + i][j] = __builtin_amdgcn_mfma_f32_16x16x32_bf16(a1[i], b4[j], acc[4 + i][j], 0, 0, 0);
    }

    // epilogue. C/D layout: col = lane&15, row = quad*4 + reg (verified)
    float sb[4]; int lbv[4];
#pragma unroll
    for (int j = 0; j < 4; ++j) {
        int cl = wc * 64 + j * 16 + rr;
        sb[j]  = sSqB[cl];
        lbv[j] = sLabB[cl];
    }

    float posS = 0.f, dmin = 1e30f;
#pragma unroll
    for (int i = 0; i < 8; ++i) {
#pragma unroll
        for (int rg = 0; rg < 4; ++rg) {
            int   rl = wr * 128 + i * 16 + quad * 4 + rg;
            float sa = sSqA[rl];
            int   la = sLabA[rl];
#pragma unroll
            for (int j = 0; j < 4; ++j) {
                float d = fmaxf(sa + sb[j] - 2.0f * acc[i][j][rg], 0.0f);
                bool same = (la == lbv[j]);
                posS += same ? d : 0.f;
                dmin = fminf(dmin, same ? 1e30f : d);
            }
        }
    }

    float negS = 0.f;
    if (__any(dmin + 1e-9f < 4.0f)) {   // rare: some hinge term is nonzero
#pragma unroll
        for (int i = 0; i < 8; ++i) {
#pragma unroll
            for (int rg = 0; rg < 4; ++rg) {
                int   rl = wr * 128 + i * 16 + quad * 4 + rg;
                float sa = sSqA[rl];
                int   la = sLabA[rl];
#pragma unroll
                for (int j = 0; j < 4; ++j) {
                    float d = fmaxf(sa + sb[j] - 2.0f * acc[i][j][rg], 0.0f);
                    float h = fmaxf(2.0f - sqrtf(d + 1e-9f), 0.f);
                    negS += (la == lbv[j]) ? 0.f : h * h;
                }
            }
        }
    }

    const float factor = (bi == bj) ? 1.0f : 2.0f;
    posS *= factor; negS *= factor;

#pragma unroll
    for (int off = 32; off > 0; off >>= 1) {
        posS += __shfl_down(posS, off);
        negS += __shfl_down(negS, off);
    }
    if (lane == 0) { rP[wave] = posS; rN[wave] = negS; }
    __syncthreads();
    if (tid == 0) {
        float tp = 0.f, tn = 0.f;
#pragma unroll
        for (int w = 0; w < 8; ++w) { tp += rP[w]; tn += rN[w]; }
        slots[k]         = tp;
        slots[NTRI2 + k] = tn;
    }
}

// --- kernel 3: label histogram (exact num_pos) + slot reduce + combine ---
__global__ __launch_bounds__(1024) void finalize_kernel(
    const float* __restrict__ slots, const int* __restrict__ lab,
    float* __restrict__ out)
{
    __shared__ int   hist[64];
    __shared__ float sP[16], sN[16];
    const int tid = threadIdx.x;
    if (tid < 64) hist[tid] = 0;
    __syncthreads();
    for (int i = tid; i < NPTS; i += 1024) atomicAdd(&hist[lab[i]], 1);

    float p = 0.f, n = 0.f;
    for (int i = tid; i < NTRI2; i += 1024) { p += slots[i]; n += slots[NTRI2 + i]; }
#pragma unroll
    for (int off = 32; off > 0; off >>= 1) {
        p += __shfl_down(p, off);
        n += __shfl_down(n, off);
    }
    const int wave = tid >> 6, lane = tid & 63;
    if (lane == 0) { sP[wave] = p; sN[wave] = n; }
    __syncthreads();
    if (tid == 0) {
        long long np = 0;
        for (int c = 0; c < 64; ++c) np += (long long)hist[c] * hist[c];
        float tp = 0.f, tn = 0.f;
#pragma unroll
        for (int w = 0; w < 16; ++w) { tp += sP[w]; tn += sN[w]; }
        double dnp = (double)np;
        double dnn = (double)NPTS * (double)NPTS - dnp;
        double pt = (dnp > 0.0) ? 0.5 * (double)tp / dnp : 0.0;
        double nt = (dnn > 0.0) ? 0.5 * (double)tn / dnn : 0.0;
        out[0] = (float)(pt + nt);
    }
}

extern "C" void kernel_launch(void* const* d_in, const int* in_sizes, int n_in,
                              void* d_out, int out_size, void* d_ws, size_t ws_size,
                              hipStream_t stream) {
    const float* X   = (const float*)d_in[0];
    const int*   lab = (const int*)d_in[1];
    float*       out = (float*)d_out;

    char* ws = (char*)d_ws;
    unsigned short* Xbf   = (unsigned short*)(ws);                      // 2 MB
    float*          sq    = (float*)(ws + 2 * 1024 * 1024);             // 32 KB
    float*          slots = (float*)(ws + 2 * 1024 * 1024 + 32 * 1024); // 4.2 KB

    prep_kernel<<<NPTS / 4, 256, 0, stream>>>(X, Xbf, sq);
    pair_kernel<<<NTRI2, 512, 0, stream>>>(Xbf, lab, sq, slots);
    finalize_kernel<<<1, 1024, 0, stream>>>(slots, lab, out);
}